// Round 11
// baseline (903.720 us; speedup 1.0000x reference)
//
#include <hip/hip_runtime.h>
#include <hip/hip_bf16.h>
#include <cstdint>
#include <cstddef>

#define HID 128
#define DIM 64
#define ROWS 16
#define TMAIN 512
#define NEWTON_ITERS 10

typedef float f32x4 __attribute__((ext_vector_type(4)));
typedef short s16x8 __attribute__((ext_vector_type(8)));
typedef unsigned int u32x2 __attribute__((ext_vector_type(2)));

__device__ __forceinline__ unsigned short f2bf(float x){
    union { float f; unsigned int u; } v; v.f = x;
    unsigned int r = v.u + 0x7FFFu + ((v.u >> 16) & 1u);
    return (unsigned short)(r >> 16);
}
__device__ __forceinline__ float bf2f(unsigned short b){
    union { unsigned int u; float f; } v; v.u = ((unsigned int)b) << 16;
    return v.f;
}
__device__ __forceinline__ unsigned pk2(float a, float b){
    union { __hip_bfloat162 h; unsigned u; } cv;
    cv.h = __float22bfloat162_rn(make_float2(a, b));
    return cv.u;
}
__device__ __forceinline__ s16x8 mk8(unsigned a, unsigned b, unsigned c, unsigned d){
    union { s16x8 s; unsigned u[4]; } t; t.u[0]=a; t.u[1]=b; t.u[2]=c; t.u[3]=d; return t.s;
}
__device__ __forceinline__ s16x8 ldfrag_f32(const float* base){
    f32x4 a = *(const f32x4*)base;
    f32x4 b = *(const f32x4*)(base + 4);
    return mk8(pk2(a[0],a[1]), pk2(a[2],a[3]), pk2(b[0],b[1]), pk2(b[2],b[3]));
}
__device__ __forceinline__ void ldfrag_hl(const float* base, s16x8& hi, s16x8& lo){
    f32x4 a = *(const f32x4*)base;
    f32x4 b = *(const f32x4*)(base + 4);
    float x[8] = {a[0],a[1],a[2],a[3],b[0],b[1],b[2],b[3]};
    union { s16x8 s; unsigned short us[8]; } H, L;
    #pragma unroll
    for (int j = 0; j < 8; ++j){
        unsigned short h = f2bf(x[j]);
        H.us[j] = h;
        L.us[j] = f2bf(x[j] - bf2f(h));
    }
    hi = H.s; lo = L.s;
}
__device__ __forceinline__ f32x4 mfma16(s16x8 a, s16x8 b, f32x4 c){
    return __builtin_amdgcn_mfma_f32_16x16x32_bf16(a, b, c, 0, 0, 0);
}
__device__ __forceinline__ void wr_hl(char* buf, int off, f32x4 v){
    unsigned short h[4], l[4];
    #pragma unroll
    for (int r = 0; r < 4; ++r){
        h[r] = f2bf(v[r]);
        l[r] = f2bf(v[r] - bf2f(h[r]));
    }
    u32x2 H, L;
    H[0] = (unsigned)h[0] | ((unsigned)h[1] << 16);
    H[1] = (unsigned)h[2] | ((unsigned)h[3] << 16);
    L[0] = (unsigned)l[0] | ((unsigned)l[1] << 16);
    L[1] = (unsigned)l[2] | ((unsigned)l[3] << 16);
    *(u32x2*)(buf + off) = H;
    *(u32x2*)(buf + 8192 + off) = L;
}
// LDS-only barrier: skips the vmcnt(0) drain __syncthreads would force.
__device__ __forceinline__ void barrier_lds(){
    asm volatile("s_waitcnt lgkmcnt(0)" ::: "memory");
    __builtin_amdgcn_s_barrier();
    asm volatile("" ::: "memory");
}

// workspace layout (bytes)
#define WS_W1MT 0          // bf16 [64][128]  (Minv @ W1^T)
#define WS_MHI  16384      // bf16 [64][64]   Minv hi (t=0 v-init)
#define WS_MLO  24576      // bf16 [64][64]   Minv lo
#define WS_W1T  32768      // bf16 [64][128]  W1^T
#define WS_W2T  49152      // bf16 [128][128] W2^T
#define WS_FLAG 81920      // u32 ready flag (memset to 0 before each launch)

// ---------------- single kernel, grid = B/ROWS + 1 ----------------
// Block NB (last): dedicated prep block — W1T/W2T bf16 transposes, M = LL^T+0.01I
// (hi/lo MFMA), Newton-Schulz x10 inverse, Mhi/Mlo + W1MT -> ws; then
// syncthreads + threadfence + release flag.  Blocks 0..NB-1: ws-independent setup
// (global weight frags, biases, encoder, traj[0] stores), acquire-spin on flag,
// load ws frags, then the proven 4-interval leapfrog loop (R9 structure).
// Deadlock-free: prep block waits on nobody; co-residency fits easily.
__global__ __launch_bounds__(TMAIN) void k_main(
    const float* __restrict__ z, const float* __restrict__ L,
    const float* __restrict__ W1, const float* __restrict__ b1,
    const float* __restrict__ W2, const float* __restrict__ b2,
    const float* __restrict__ w3, const float* __restrict__ qW,
    const float* __restrict__ qb, const float* __restrict__ pW,
    const float* __restrict__ pb, const int* __restrict__ nsp,
    char* __restrict__ ws, float* __restrict__ out, int NB)
{
    __shared__ __align__(16) char shm[51712];
    const int tid = threadIdx.x;
    unsigned int* flagp = (unsigned int*)(ws + WS_FLAG);

    if (blockIdx.x == (unsigned)NB){
        // ================= PREP BLOCK =================
        // W1^T / W2^T bf16 transposes (global->global)
        {
            unsigned short* w1t = (unsigned short*)(ws + WS_W1T);
            unsigned short* w2t = (unsigned short*)(ws + WS_W2T);
            for (int i = tid; i < HID*DIM; i += TMAIN){
                int h = i >> 6, d = i & 63;
                w1t[d*HID + h] = f2bf(W1[i]);
            }
            for (int i = tid; i < HID*HID; i += TMAIN){
                int c2 = i >> 7, c1 = i & 127;
                w2t[c1*HID + c2] = f2bf(W2[i]);
            }
        }
        char* const bufA = shm;            // X hi/lo
        char* const bufB = shm + 16384;
        char* const bufC = shm + 32768;    // M hi/lo
        float* const fscr = (float*)(shm + 49152);

        const int w = tid >> 6, lane = tid & 63;
        const int l15 = lane & 15, l4 = lane >> 4;
        const int sw = (l15 & 7) << 4;
        const int rt = w & 3, ct0 = (w >> 2) * 2;

        // M = L L^T + 0.01 I via hi/lo MFMA; transposed+swizzled in bufC
        {
            s16x8 Ah[2], Al[2];
            #pragma unroll
            for (int kt = 0; kt < 2; ++kt)
                ldfrag_hl(L + (size_t)(16*rt + l15)*DIM + kt*32 + 8*l4, Ah[kt], Al[kt]);
            #pragma unroll
            for (int ct = 0; ct < 2; ++ct){
                const int n = 16*(ct0+ct) + l15;
                f32x4 acc = {0.f,0.f,0.f,0.f};
                #pragma unroll
                for (int kt = 0; kt < 2; ++kt){
                    s16x8 Bh, Bl;
                    ldfrag_hl(L + (size_t)n*DIM + kt*32 + 8*l4, Bh, Bl);
                    acc = mfma16(Ah[kt], Bh, acc);
                    acc = mfma16(Ah[kt], Bl, acc);
                    acc = mfma16(Al[kt], Bh, acc);
                }
                #pragma unroll
                for (int r = 0; r < 4; ++r)
                    if (16*rt + 4*l4 + r == n) acc[r] += 0.01f;
                wr_hl(bufC, n*128 + ((32*rt + 8*l4) ^ sw), acc);
            }
        }
        barrier_lds();
        // Gershgorin row sums
        {
            const int r = tid >> 3, c8 = (tid & 7) * 8;
            const unsigned short* mh = (const unsigned short*)bufC;
            s16x8 mv = *(const s16x8*)&mh[r*64 + (c8 ^ ((r&7)<<3))];
            float s = 0.f;
            #pragma unroll
            for (int j = 0; j < 8; ++j) s += fabsf(bf2f((unsigned short)mv[j]));
            fscr[tid] = s;
        }
        barrier_lds();
        if (tid < 64){
            float s = 0.f;
            #pragma unroll
            for (int j = 0; j < 8; ++j) s += fscr[tid*8 + j];
            fscr[512 + tid] = s;
        }
        barrier_lds();
        // c via shuffle-max, X0 = c I, M A-frags
        s16x8 Mh[2], Ml[2];
        {
            float mrs = fscr[512 + lane];
            #pragma unroll
            for (int off = 1; off < 64; off <<= 1)
                mrs = fmaxf(mrs, __shfl_xor(mrs, off));
            const float cN = 0.995f / mrs;
            const int r = tid >> 3, c8 = (tid & 7) * 8;
            union { s16x8 s; unsigned short us[8]; } Xh, Xl;
            #pragma unroll
            for (int j = 0; j < 8; ++j){ Xh.us[j] = 0; Xl.us[j] = 0; }
            const int d = r - c8;
            if (d >= 0 && d < 8){
                unsigned short h = f2bf(cN);
                Xh.us[d] = h;
                Xl.us[d] = f2bf(cN - bf2f(h));
            }
            const int idx = r*64 + (c8 ^ ((r&7)<<3));
            *(s16x8*)((unsigned short*)bufA + idx) = Xh.s;
            *(s16x8*)((unsigned short*)(bufA + 8192) + idx) = Xl.s;
            #pragma unroll
            for (int kt = 0; kt < 2; ++kt){
                const int ao = (16*rt + l15)*128 + ((kt*64 + 16*l4) ^ sw);
                Mh[kt] = *(const s16x8*)(bufC + ao);
                Ml[kt] = *(const s16x8*)(bufC + 8192 + ao);
            }
        }
        barrier_lds();
        // Newton-Schulz (transposed hi/lo storage)
        {
            char* pX = bufA; char* pY = bufB; char* pS = bufC;
            for (int it = 0; it < NEWTON_ITERS; ++it){
                #pragma unroll
                for (int ct = 0; ct < 2; ++ct){
                    const int n = 16*(ct0+ct) + l15;
                    f32x4 acc = {0.f,0.f,0.f,0.f};
                    #pragma unroll
                    for (int kt = 0; kt < 2; ++kt){
                        const int bo = n*128 + ((kt*64 + 16*l4) ^ sw);
                        s16x8 bh = *(const s16x8*)(pX + bo);
                        s16x8 bl = *(const s16x8*)(pX + 8192 + bo);
                        acc = mfma16(Mh[kt], bh, acc);
                        acc = mfma16(Mh[kt], bl, acc);
                        acc = mfma16(Ml[kt], bh, acc);
                    }
                    wr_hl(pY, n*128 + ((32*rt + 8*l4) ^ sw), acc);
                }
                barrier_lds();
                #pragma unroll
                for (int ct = 0; ct < 2; ++ct){
                    const int n = 16*(ct0+ct) + l15;
                    f32x4 acc = {0.f,0.f,0.f,0.f};
                    #pragma unroll
                    for (int kt = 0; kt < 2; ++kt){
                        const int ao = (16*rt + l15)*128 + ((kt*64 + 16*l4) ^ sw);
                        s16x8 ah = *(const s16x8*)(pY + ao);
                        s16x8 al = *(const s16x8*)(pY + 8192 + ao);
                        const int bo = n*128 + ((kt*64 + 16*l4) ^ sw);
                        s16x8 bh = *(const s16x8*)(pX + bo);
                        s16x8 bl = *(const s16x8*)(pX + 8192 + bo);
                        acc = mfma16(ah, bh, acc);
                        acc = mfma16(ah, bl, acc);
                        acc = mfma16(al, bh, acc);
                    }
                    const int xo = n*128 + ((32*rt + 8*l4) ^ sw);
                    u32x2 H = *(const u32x2*)(pX + xo);
                    u32x2 Lo = *(const u32x2*)(pX + 8192 + xo);
                    f32x4 nx;
                    #pragma unroll
                    for (int r = 0; r < 4; ++r){
                        unsigned hu = (r < 2) ? H[0] : H[1];
                        unsigned lu = (r < 2) ? Lo[0] : Lo[1];
                        unsigned short hh = (unsigned short)((r & 1) ? (hu >> 16) : (hu & 0xffff));
                        unsigned short ll = (unsigned short)((r & 1) ? (lu >> 16) : (lu & 0xffff));
                        float xv = bf2f(hh) + bf2f(ll);
                        nx[r] = 2.0f * xv - acc[r];
                    }
                    wr_hl(pS, xo, nx);
                }
                barrier_lds();
                char* t = pX; pX = pS; pS = pY; pY = t;   // even iters -> X back in bufA
            }
        }
        // Mhi/Mlo -> ws (unswizzled linear)
        {
            unsigned short* mhi = (unsigned short*)(ws + WS_MHI);
            unsigned short* mlo = (unsigned short*)(ws + WS_MLO);
            const unsigned short* xh = (const unsigned short*)bufA;
            const unsigned short* xl = (const unsigned short*)(bufA + 8192);
            for (int i = tid; i < 4096; i += TMAIN){
                int r = i >> 6, c = i & 63;
                int si = r*64 + (c ^ ((r&7)<<3));
                mhi[i] = xh[si];
                mlo[i] = xl[si];
            }
        }
        // W1MT = Minv @ W1^T via MFMA -> ws
        {
            const int h0 = w * 16;
            s16x8 fB0 = ldfrag_f32(W1 + (size_t)(h0+l15)*DIM + 8*l4);
            s16x8 fB1 = ldfrag_f32(W1 + (size_t)(h0+l15)*DIM + 32 + 8*l4);
            const unsigned short* xh = (const unsigned short*)bufA;
            const unsigned short* xl = (const unsigned short*)(bufA + 8192);
            unsigned short* w1mt = (unsigned short*)(ws + WS_W1MT);
            #pragma unroll
            for (int d0 = 0; d0 < 64; d0 += 16){
                f32x4 acc = {0.f,0.f,0.f,0.f};
                const int u0 = (d0+l15)*64 + ((8*l4) ^ ((l15&7)<<3));
                const int u1 = (d0+l15)*64 + ((32 + 8*l4) ^ ((l15&7)<<3));
                acc = mfma16(*(const s16x8*)&xh[u0], fB0, acc);
                acc = mfma16(*(const s16x8*)&xl[u0], fB0, acc);
                acc = mfma16(*(const s16x8*)&xh[u1], fB1, acc);
                acc = mfma16(*(const s16x8*)&xl[u1], fB1, acc);
                #pragma unroll
                for (int r = 0; r < 4; ++r)
                    w1mt[(size_t)(d0 + 4*l4 + r)*HID + h0 + l15] = f2bf(acc[r]);
            }
        }
        __syncthreads();                    // all waves' stores drained (vmcnt 0)
        if (tid == 0){
            __threadfence();                // publish ws device-wide
            __hip_atomic_store(flagp, 1u, __ATOMIC_RELEASE, __HIP_MEMORY_SCOPE_AGENT);
        }
        return;
    }

    // ================= ROW BLOCKS =================
    char* const sQb_ = shm;             // bf16 [16][64]   2048
    char* const sPb_ = shm + 2048;      // bf16 [16][64]   2048
    char* const sA1_ = shm + 4096;      // bf16 [16][128]  4096
    char* const sG2_ = shm + 8192;      // bf16 [16][128]  4096
    char* const sG1_ = shm + 12288;     // bf16 [16][128]  4096
    char* const sD1_ = shm + 16384;     // f32  [16][128]  8192

    const int w = tid >> 6, lane = tid & 63;
    const int l15 = lane & 15, l4 = lane >> 4;
    const int sw = (l15 & 7) << 4;
    const int m0 = w * 16;
    const int wq = w & 3;
    const int mq = wq * 16;
    const bool isQ = (w >= 4);
    const int NS = *nsp;
    const float dtv = 1.0f / (float)NS;   // T_SPAN = (0,1)
    const int TS = (NS + 1) * 128;
    const int b0 = blockIdx.x * ROWS;

    // ---- ws-independent setup first (overlaps prep block) ----
    s16x8 fW1[2], fW2[4];
    #pragma unroll
    for (int kt = 0; kt < 2; ++kt)
        fW1[kt] = ldfrag_f32(W1 + (size_t)(m0+l15)*DIM + kt*32 + 8*l4);
    #pragma unroll
    for (int kt = 0; kt < 4; ++kt)
        fW2[kt] = ldfrag_f32(W2 + (size_t)(m0+l15)*HID + kt*32 + 8*l4);
    const f32x4 bb1 = *(const f32x4*)&b1[m0 + 4*l4];
    const f32x4 bb2 = *(const f32x4*)&b2[m0 + 4*l4];
    const f32x4 bw3 = *(const f32x4*)&w3[m0 + 4*l4];

    // strength-reduced traj pointers (advance by 128 per step)
    float* ptr_q = out + (size_t)(b0+l15)*TS + mq + 4*l4;        // q slot, step 0
    float* ptr_p = out + (size_t)(b0+l15)*TS + 64 + mq + 4*l4;   // p slot, step 0

    // encoder: waves4-7 -> q0, waves0-3 -> p0 (masters in registers)
    f32x4 master;
    {
        const float* zr = z + (size_t)(b0 + l15) * DIM;
        s16x8 bz0 = ldfrag_f32(zr + 8*l4);
        s16x8 bz1 = ldfrag_f32(zr + 32 + 8*l4);
        const float* eW = isQ ? qW : pW;
        const float* eb = isQ ? qb : pb;
        const float* wr = eW + (size_t)(mq + l15) * DIM;
        s16x8 fE0 = ldfrag_f32(wr + 8*l4);
        s16x8 fE1 = ldfrag_f32(wr + 32 + 8*l4);
        f32x4 acc = {0.f,0.f,0.f,0.f};
        acc = mfma16(fE0, bz0, acc);
        acc = mfma16(fE1, bz1, acc);
        f32x4 be = *(const f32x4*)&eb[mq + 4*l4];
        master = acc + be;
        if (isQ){
            u32x2 pr; pr[0] = pk2(master[0],master[1]); pr[1] = pk2(master[2],master[3]);
            *(u32x2*)(sQb_ + l15*128 + ((32*wq + 8*l4) ^ sw)) = pr;
        }
        *(f32x4*)(isQ ? ptr_q : ptr_p) = master;
    }

    // ---- wait for prep block (acquire) ----
    while (__hip_atomic_load(flagp, __ATOMIC_ACQUIRE, __HIP_MEMORY_SCOPE_AGENT) == 0u)
        __builtin_amdgcn_s_sleep(4);

    // ---- ws-dependent fragments ----
    const unsigned short* wsW1MT = (const unsigned short*)(ws + WS_W1MT);
    const unsigned short* wsW1T  = (const unsigned short*)(ws + WS_W1T);
    const unsigned short* wsW2T  = (const unsigned short*)(ws + WS_W2T);
    const unsigned short* wsMhi  = (const unsigned short*)(ws + WS_MHI);
    const unsigned short* wsMlo  = (const unsigned short*)(ws + WS_MLO);

    s16x8 fW2T[4], fP4[4];
    #pragma unroll
    for (int kt = 0; kt < 4; ++kt)
        fW2T[kt] = *(const s16x8*)&wsW2T[(m0+l15)*HID + kt*32 + 8*l4];
    {
        const unsigned short* wp4 = isQ ? wsW1MT : wsW1T;
        #pragma unroll
        for (int kt = 0; kt < 4; ++kt)
            fP4[kt] = *(const s16x8*)&wp4[(mq+l15)*HID + kt*32 + 8*l4];
    }
    barrier_lds();

    f32x4 vm = {0.f,0.f,0.f,0.f};
    f32x4 pend = {0.f,0.f,0.f,0.f};

    for (int t = 0; t <= NS; ++t){
        // ---- P1: deferred traj stores, then h1 = q@W1^T + b1 ----
        {
            if (t >= 1){
                if (isQ){
                    ptr_q += 128;
                    *(f32x4*)ptr_q = pend;
                } else if (t >= 2){
                    ptr_p += 128;
                    *(f32x4*)ptr_p = pend;
                }
            }
            s16x8 bq0 = *(const s16x8*)(sQb_ + l15*128 + ((16*l4) ^ sw));
            s16x8 bq1 = *(const s16x8*)(sQb_ + l15*128 + ((64 + 16*l4) ^ sw));
            f32x4 a0 = {0.f,0.f,0.f,0.f}, a1v = {0.f,0.f,0.f,0.f};
            a0 = mfma16(fW1[0], bq0, a0);
            a1v = mfma16(fW1[1], bq1, a1v);
            f32x4 si, dv;
            #pragma unroll
            for (int r = 0; r < 4; ++r){
                float h = a0[r] + a1v[r] + bb1[r];
                float sg = 1.0f / (1.0f + __expf(-h));
                float s = h * sg;
                si[r] = s;
                dv[r] = sg + s * (1.0f - sg);
            }
            u32x2 pr; pr[0] = pk2(si[0],si[1]); pr[1] = pk2(si[2],si[3]);
            *(u32x2*)(sA1_ + l15*256 + ((2*m0 + 8*l4) ^ sw)) = pr;
            *(f32x4*)(sD1_ + l15*512 + ((4*m0 + 16*l4) ^ sw)) = dv;
        }
        barrier_lds();
        // ---- P2: h2 = a1@W2^T + b2 ; g2 = w3 * silu'(h2) ----
        {
            f32x4 a0 = {0.f,0.f,0.f,0.f}, a1v = {0.f,0.f,0.f,0.f};
            #pragma unroll
            for (int kt = 0; kt < 2; ++kt){
                s16x8 ba0 = *(const s16x8*)(sA1_ + l15*256 + ((64*(2*kt) + 16*l4) ^ sw));
                s16x8 ba1 = *(const s16x8*)(sA1_ + l15*256 + ((64*(2*kt+1) + 16*l4) ^ sw));
                a0 = mfma16(fW2[2*kt], ba0, a0);
                a1v = mfma16(fW2[2*kt+1], ba1, a1v);
            }
            f32x4 g2;
            #pragma unroll
            for (int r = 0; r < 4; ++r){
                float h = a0[r] + a1v[r] + bb2[r];
                float sg = 1.0f / (1.0f + __expf(-h));
                g2[r] = bw3[r] * (sg * (1.0f + h * (1.0f - sg)));
            }
            u32x2 pr; pr[0] = pk2(g2[0],g2[1]); pr[1] = pk2(g2[2],g2[3]);
            *(u32x2*)(sG2_ + l15*256 + ((2*m0 + 8*l4) ^ sw)) = pr;
        }
        barrier_lds();
        // ---- P3: g1 = (g2 @ W2) * d1 ----
        {
            f32x4 a0 = {0.f,0.f,0.f,0.f}, a1v = {0.f,0.f,0.f,0.f};
            #pragma unroll
            for (int kt = 0; kt < 2; ++kt){
                s16x8 bg0 = *(const s16x8*)(sG2_ + l15*256 + ((64*(2*kt) + 16*l4) ^ sw));
                s16x8 bg1 = *(const s16x8*)(sG2_ + l15*256 + ((64*(2*kt+1) + 16*l4) ^ sw));
                a0 = mfma16(fW2T[2*kt], bg0, a0);
                a1v = mfma16(fW2T[2*kt+1], bg1, a1v);
            }
            f32x4 dv = *(const f32x4*)(sD1_ + l15*512 + ((4*m0 + 16*l4) ^ sw));
            f32x4 g1;
            #pragma unroll
            for (int r = 0; r < 4; ++r) g1[r] = (a0[r] + a1v[r]) * dv[r];
            u32x2 pr; pr[0] = pk2(g1[0],g1[1]); pr[1] = pk2(g1[2],g1[3]);
            *(u32x2*)(sG1_ + l15*256 + ((2*m0 + 8*l4) ^ sw)) = pr;
        }
        barrier_lds();
        // ---- P4: w<4: grad=g1@W1T -> p; w>=4: wv=g1@W1MT -> v,q ----
        if (!isQ){
            f32x4 a0 = {0.f,0.f,0.f,0.f}, a1v = {0.f,0.f,0.f,0.f};
            #pragma unroll
            for (int kt = 0; kt < 2; ++kt){
                s16x8 bg0 = *(const s16x8*)(sG1_ + l15*256 + ((64*(2*kt) + 16*l4) ^ sw));
                s16x8 bg1 = *(const s16x8*)(sG1_ + l15*256 + ((64*(2*kt+1) + 16*l4) ^ sw));
                a0 = mfma16(fP4[2*kt], bg0, a0);
                a1v = mfma16(fP4[2*kt+1], bg1, a1v);
            }
            if (t == 0){
                #pragma unroll
                for (int r = 0; r < 4; ++r) master[r] -= 0.5f * dtv * (a0[r] + a1v[r]);
                u32x2 pr; pr[0] = pk2(master[0],master[1]); pr[1] = pk2(master[2],master[3]);
                *(u32x2*)(sPb_ + l15*128 + ((32*wq + 8*l4) ^ sw)) = pr;
            } else {
                #pragma unroll
                for (int r = 0; r < 4; ++r){
                    float g = a0[r] + a1v[r];
                    pend[r] = master[r] - 0.5f * dtv * g;   // p(t)
                    master[r] -= dtv * g;                    // p_half(t+1/2)
                }
            }
        } else if (t >= 1){
            f32x4 a0 = {0.f,0.f,0.f,0.f}, a1v = {0.f,0.f,0.f,0.f};
            #pragma unroll
            for (int kt = 0; kt < 2; ++kt){
                s16x8 bg0 = *(const s16x8*)(sG1_ + l15*256 + ((64*(2*kt) + 16*l4) ^ sw));
                s16x8 bg1 = *(const s16x8*)(sG1_ + l15*256 + ((64*(2*kt+1) + 16*l4) ^ sw));
                a0 = mfma16(fP4[2*kt], bg0, a0);
                a1v = mfma16(fP4[2*kt+1], bg1, a1v);
            }
            #pragma unroll
            for (int r = 0; r < 4; ++r){
                vm[r] -= dtv * (a0[r] + a1v[r]);   // v(t+1/2)
                master[r] += dtv * vm[r];          // q(t+1)
            }
            u32x2 pr; pr[0] = pk2(master[0],master[1]); pr[1] = pk2(master[2],master[3]);
            *(u32x2*)(sQb_ + l15*128 + ((32*wq + 8*l4) ^ sw)) = pr;
            pend = master;
        }
        barrier_lds();
        // ---- one-time v init after the first half-kick ----
        if (t == 0){
            if (isQ){
                s16x8 fMhi[2], fMlo[2];
                #pragma unroll
                for (int kt = 0; kt < 2; ++kt){
                    fMhi[kt] = *(const s16x8*)&wsMhi[(mq+l15)*DIM + kt*32 + 8*l4];
                    fMlo[kt] = *(const s16x8*)&wsMlo[(mq+l15)*DIM + kt*32 + 8*l4];
                }
                s16x8 bp0 = *(const s16x8*)(sPb_ + l15*128 + ((16*l4) ^ sw));
                s16x8 bp1 = *(const s16x8*)(sPb_ + l15*128 + ((64 + 16*l4) ^ sw));
                f32x4 aH = {0.f,0.f,0.f,0.f}, aL = {0.f,0.f,0.f,0.f};
                aH = mfma16(fMhi[0], bp0, aH);
                aH = mfma16(fMhi[1], bp1, aH);
                aL = mfma16(fMlo[0], bp0, aL);
                aL = mfma16(fMlo[1], bp1, aL);
                #pragma unroll
                for (int r = 0; r < 4; ++r){
                    vm[r] = aH[r] + aL[r];         // v(1/2)
                    master[r] += dtv * vm[r];      // q(1)
                }
                u32x2 pr; pr[0] = pk2(master[0],master[1]); pr[1] = pk2(master[2],master[3]);
                *(u32x2*)(sQb_ + l15*128 + ((32*wq + 8*l4) ^ sw)) = pr;
                pend = master;
            }
            barrier_lds();
        }
    }
    // flush last p-traj
    if (!isQ)
        *(f32x4*)(ptr_p + 128) = pend;
}

extern "C" void kernel_launch(void* const* d_in, const int* in_sizes, int n_in,
                              void* d_out, int out_size, void* d_ws, size_t ws_size,
                              hipStream_t stream)
{
    const float* z  = (const float*)d_in[0];
    const float* L  = (const float*)d_in[1];
    const float* W1 = (const float*)d_in[2];
    const float* b1 = (const float*)d_in[3];
    const float* W2 = (const float*)d_in[4];
    const float* b2 = (const float*)d_in[5];
    const float* w3 = (const float*)d_in[6];
    // d_in[7] = Vb3: constant, vanishes in gradV
    const float* qW = (const float*)d_in[8];
    const float* qb = (const float*)d_in[9];
    const float* pW = (const float*)d_in[10];
    const float* pb = (const float*)d_in[11];
    const int* nsp  = (const int*)d_in[12];
    float* out = (float*)d_out;
    char* ws = (char*)d_ws;
    const int B = in_sizes[0] / DIM;
    const int NB = B / ROWS;

    hipMemsetAsync(ws + WS_FLAG, 0, 4, stream);   // reset ready flag each launch
    k_main<<<NB + 1, TMAIN, 0, stream>>>(z, L, W1, b1, W2, b2, w3, qW, qb, pW, pb,
                                         nsp, ws, out, NB);
}

// Round 12
// 129.051 us; speedup vs baseline: 7.0028x; 7.0028x over previous
//
#include <hip/hip_runtime.h>
#include <hip/hip_bf16.h>
#include <cstdint>
#include <cstddef>

#define HID 128
#define DIM 64
#define ROWS 16
#define TMAIN 512
#define NEWTON_ITERS 10

typedef float f32x4 __attribute__((ext_vector_type(4)));
typedef short s16x8 __attribute__((ext_vector_type(8)));
typedef unsigned int u32x2 __attribute__((ext_vector_type(2)));

__device__ __forceinline__ unsigned short f2bf(float x){
    union { float f; unsigned int u; } v; v.f = x;
    unsigned int r = v.u + 0x7FFFu + ((v.u >> 16) & 1u);
    return (unsigned short)(r >> 16);
}
__device__ __forceinline__ float bf2f(unsigned short b){
    union { unsigned int u; float f; } v; v.u = ((unsigned int)b) << 16;
    return v.f;
}
__device__ __forceinline__ unsigned pk2(float a, float b){
    union { __hip_bfloat162 h; unsigned u; } cv;
    cv.h = __float22bfloat162_rn(make_float2(a, b));
    return cv.u;
}
__device__ __forceinline__ s16x8 mk8(unsigned a, unsigned b, unsigned c, unsigned d){
    union { s16x8 s; unsigned u[4]; } t; t.u[0]=a; t.u[1]=b; t.u[2]=c; t.u[3]=d; return t.s;
}
__device__ __forceinline__ s16x8 ldfrag_f32(const float* base){
    f32x4 a = *(const f32x4*)base;
    f32x4 b = *(const f32x4*)(base + 4);
    return mk8(pk2(a[0],a[1]), pk2(a[2],a[3]), pk2(b[0],b[1]), pk2(b[2],b[3]));
}
__device__ __forceinline__ void ldfrag_hl(const float* base, s16x8& hi, s16x8& lo){
    f32x4 a = *(const f32x4*)base;
    f32x4 b = *(const f32x4*)(base + 4);
    float x[8] = {a[0],a[1],a[2],a[3],b[0],b[1],b[2],b[3]};
    union { s16x8 s; unsigned short us[8]; } H, L;
    #pragma unroll
    for (int j = 0; j < 8; ++j){
        unsigned short h = f2bf(x[j]);
        H.us[j] = h;
        L.us[j] = f2bf(x[j] - bf2f(h));
    }
    hi = H.s; lo = L.s;
}
__device__ __forceinline__ f32x4 mfma16(s16x8 a, s16x8 b, f32x4 c){
    return __builtin_amdgcn_mfma_f32_16x16x32_bf16(a, b, c, 0, 0, 0);
}
__device__ __forceinline__ void wr_hl(char* buf, int off, f32x4 v){
    unsigned short h[4], l[4];
    #pragma unroll
    for (int r = 0; r < 4; ++r){
        h[r] = f2bf(v[r]);
        l[r] = f2bf(v[r] - bf2f(h[r]));
    }
    u32x2 H, L;
    H[0] = (unsigned)h[0] | ((unsigned)h[1] << 16);
    H[1] = (unsigned)h[2] | ((unsigned)h[3] << 16);
    L[0] = (unsigned)l[0] | ((unsigned)l[1] << 16);
    L[1] = (unsigned)l[2] | ((unsigned)l[3] << 16);
    *(u32x2*)(buf + off) = H;
    *(u32x2*)(buf + 8192 + off) = L;
}
// LDS-only barrier: skips the vmcnt(0) drain __syncthreads would force.
__device__ __forceinline__ void barrier_lds(){
    asm volatile("s_waitcnt lgkmcnt(0)" ::: "memory");
    __builtin_amdgcn_s_barrier();
    asm volatile("" ::: "memory");
}

// workspace layout (bytes) — 81920 used
#define WS_W1MT 0          // bf16 [64][128]  (Minv @ W1^T)
#define WS_MHI  16384      // bf16 [64][64]   Minv hi (t=0 v-init)
#define WS_MLO  24576      // bf16 [64][64]   Minv lo
#define WS_W1T  32768      // bf16 [64][128]  W1^T
#define WS_W2T  49152      // bf16 [128][128] W2^T

// ---------------- kernel 1 (2 blocks): block0 = Newton-Schulz inverse + W1MT;
//                  block1 = transposed weight bf16 prep ----------------
__global__ __launch_bounds__(512) void k_prep(
    const float* __restrict__ L, const float* __restrict__ W1,
    const float* __restrict__ W2, char* __restrict__ ws)
{
    const int tid = threadIdx.x;
    if (blockIdx.x == 1){
        unsigned short* w1t = (unsigned short*)(ws + WS_W1T);
        unsigned short* w2t = (unsigned short*)(ws + WS_W2T);
        for (int i = tid; i < HID*DIM; i += 512){
            int h = i >> 6, d = i & 63;
            w1t[d*HID + h] = f2bf(W1[i]);
        }
        for (int i = tid; i < HID*HID; i += 512){
            int c2 = i >> 7, c1 = i & 127;
            w2t[c1*HID + c2] = f2bf(W2[i]);
        }
        return;
    }
    // ---- block 0: M = LL^T + 0.01I -> Newton-Schulz x10 -> Mhi/Mlo + W1MT ----
    __shared__ __align__(16) char nbuf[51712];
    char* const bufA = nbuf;            // X hi/lo (16KB: hi 8K, lo 8K)
    char* const bufB = nbuf + 16384;
    char* const bufC = nbuf + 32768;    // M hi/lo
    float* const fscr = (float*)(nbuf + 49152);

    const int w = tid >> 6, lane = tid & 63;
    const int l15 = lane & 15, l4 = lane >> 4;
    const int sw = (l15 & 7) << 4;      // byte swizzle, 16B granule
    const int rt = w & 3, ct0 = (w >> 2) * 2;

    // M = L L^T + 0.01 I via hi/lo MFMA; store transposed+swizzled in bufC
    {
        s16x8 Ah[2], Al[2];
        #pragma unroll
        for (int kt = 0; kt < 2; ++kt)
            ldfrag_hl(L + (size_t)(16*rt + l15)*DIM + kt*32 + 8*l4, Ah[kt], Al[kt]);
        #pragma unroll
        for (int ct = 0; ct < 2; ++ct){
            const int n = 16*(ct0+ct) + l15;
            f32x4 acc = {0.f,0.f,0.f,0.f};
            #pragma unroll
            for (int kt = 0; kt < 2; ++kt){
                s16x8 Bh, Bl;
                ldfrag_hl(L + (size_t)n*DIM + kt*32 + 8*l4, Bh, Bl);
                acc = mfma16(Ah[kt], Bh, acc);
                acc = mfma16(Ah[kt], Bl, acc);
                acc = mfma16(Al[kt], Bh, acc);
            }
            #pragma unroll
            for (int r = 0; r < 4; ++r)
                if (16*rt + 4*l4 + r == n) acc[r] += 0.01f;
            wr_hl(bufC, n*128 + ((32*rt + 8*l4) ^ sw), acc);
        }
    }
    barrier_lds();

    // Gershgorin row sums of |M|
    {
        const int r = tid >> 3, c8 = (tid & 7) * 8;
        const unsigned short* mh = (const unsigned short*)bufC;
        s16x8 mv = *(const s16x8*)&mh[r*64 + (c8 ^ ((r&7)<<3))];
        float s = 0.f;
        #pragma unroll
        for (int j = 0; j < 8; ++j) s += fabsf(bf2f((unsigned short)mv[j]));
        fscr[tid] = s;
    }
    barrier_lds();
    if (tid < 64){
        float s = 0.f;
        #pragma unroll
        for (int j = 0; j < 8; ++j) s += fscr[tid*8 + j];
        fscr[512 + tid] = s;
    }
    barrier_lds();

    // c via shuffle-max, X0 = c I, M A-frags to registers
    s16x8 Mh[2], Ml[2];
    {
        float mrs = fscr[512 + lane];
        #pragma unroll
        for (int off = 1; off < 64; off <<= 1)
            mrs = fmaxf(mrs, __shfl_xor(mrs, off));
        const float cN = 0.995f / mrs;
        const int r = tid >> 3, c8 = (tid & 7) * 8;
        union { s16x8 s; unsigned short us[8]; } Xh, Xl;
        #pragma unroll
        for (int j = 0; j < 8; ++j){ Xh.us[j] = 0; Xl.us[j] = 0; }
        const int d = r - c8;
        if (d >= 0 && d < 8){
            unsigned short h = f2bf(cN);
            Xh.us[d] = h;
            Xl.us[d] = f2bf(cN - bf2f(h));
        }
        const int idx = r*64 + (c8 ^ ((r&7)<<3));
        *(s16x8*)((unsigned short*)bufA + idx) = Xh.s;
        *(s16x8*)((unsigned short*)(bufA + 8192) + idx) = Xl.s;
        #pragma unroll
        for (int kt = 0; kt < 2; ++kt){
            const int ao = (16*rt + l15)*128 + ((kt*64 + 16*l4) ^ sw);
            Mh[kt] = *(const s16x8*)(bufC + ao);
            Ml[kt] = *(const s16x8*)(bufC + 8192 + ao);
        }
    }
    barrier_lds();

    // Newton-Schulz x10 (stored transposed; Minv symmetric)
    {
        char* pX = bufA; char* pY = bufB; char* pS = bufC;
        for (int it = 0; it < NEWTON_ITERS; ++it){
            #pragma unroll
            for (int ct = 0; ct < 2; ++ct){
                const int n = 16*(ct0+ct) + l15;
                f32x4 acc = {0.f,0.f,0.f,0.f};
                #pragma unroll
                for (int kt = 0; kt < 2; ++kt){
                    const int bo = n*128 + ((kt*64 + 16*l4) ^ sw);
                    s16x8 bh = *(const s16x8*)(pX + bo);
                    s16x8 bl = *(const s16x8*)(pX + 8192 + bo);
                    acc = mfma16(Mh[kt], bh, acc);
                    acc = mfma16(Mh[kt], bl, acc);
                    acc = mfma16(Ml[kt], bh, acc);
                }
                wr_hl(pY, n*128 + ((32*rt + 8*l4) ^ sw), acc);
            }
            barrier_lds();
            #pragma unroll
            for (int ct = 0; ct < 2; ++ct){
                const int n = 16*(ct0+ct) + l15;
                f32x4 acc = {0.f,0.f,0.f,0.f};
                #pragma unroll
                for (int kt = 0; kt < 2; ++kt){
                    const int ao = (16*rt + l15)*128 + ((kt*64 + 16*l4) ^ sw);
                    s16x8 ah = *(const s16x8*)(pY + ao);
                    s16x8 al = *(const s16x8*)(pY + 8192 + ao);
                    const int bo = n*128 + ((kt*64 + 16*l4) ^ sw);
                    s16x8 bh = *(const s16x8*)(pX + bo);
                    s16x8 bl = *(const s16x8*)(pX + 8192 + bo);
                    acc = mfma16(ah, bh, acc);
                    acc = mfma16(ah, bl, acc);
                    acc = mfma16(al, bh, acc);
                }
                const int xo = n*128 + ((32*rt + 8*l4) ^ sw);
                u32x2 H = *(const u32x2*)(pX + xo);
                u32x2 Lo = *(const u32x2*)(pX + 8192 + xo);
                f32x4 nx;
                #pragma unroll
                for (int r = 0; r < 4; ++r){
                    unsigned hu = (r < 2) ? H[0] : H[1];
                    unsigned lu = (r < 2) ? Lo[0] : Lo[1];
                    unsigned short hh = (unsigned short)((r & 1) ? (hu >> 16) : (hu & 0xffff));
                    unsigned short ll = (unsigned short)((r & 1) ? (lu >> 16) : (lu & 0xffff));
                    float xv = bf2f(hh) + bf2f(ll);
                    nx[r] = 2.0f * xv - acc[r];
                }
                wr_hl(pS, xo, nx);
            }
            barrier_lds();
            char* t = pX; pX = pS; pS = pY; pY = t;   // even iters -> X back in bufA
        }
    }

    // Mhi/Mlo -> ws, unswizzled linear [64][64]
    {
        unsigned short* mhi = (unsigned short*)(ws + WS_MHI);
        unsigned short* mlo = (unsigned short*)(ws + WS_MLO);
        const unsigned short* xh = (const unsigned short*)bufA;
        const unsigned short* xl = (const unsigned short*)(bufA + 8192);
        for (int i = tid; i < 4096; i += 512){
            int r = i >> 6, c = i & 63;
            int si = r*64 + (c ^ ((r&7)<<3));
            mhi[i] = xh[si];
            mlo[i] = xl[si];
        }
    }

    // W1MT = Minv @ W1^T via MFMA (A = X hi/lo swizzled in bufA, B = W1 rows) -> ws
    {
        const int h0 = w * 16;
        s16x8 fB0 = ldfrag_f32(W1 + (size_t)(h0+l15)*DIM + 8*l4);
        s16x8 fB1 = ldfrag_f32(W1 + (size_t)(h0+l15)*DIM + 32 + 8*l4);
        const unsigned short* xh = (const unsigned short*)bufA;
        const unsigned short* xl = (const unsigned short*)(bufA + 8192);
        unsigned short* w1mt = (unsigned short*)(ws + WS_W1MT);
        #pragma unroll
        for (int d0 = 0; d0 < 64; d0 += 16){
            f32x4 acc = {0.f,0.f,0.f,0.f};
            const int u0 = (d0+l15)*64 + ((8*l4) ^ ((l15&7)<<3));
            const int u1 = (d0+l15)*64 + ((32 + 8*l4) ^ ((l15&7)<<3));
            acc = mfma16(*(const s16x8*)&xh[u0], fB0, acc);
            acc = mfma16(*(const s16x8*)&xl[u0], fB0, acc);
            acc = mfma16(*(const s16x8*)&xh[u1], fB1, acc);
            acc = mfma16(*(const s16x8*)&xl[u1], fB1, acc);
            #pragma unroll
            for (int r = 0; r < 4; ++r)
                w1mt[(size_t)(d0 + 4*l4 + r)*HID + h0 + l15] = f2bf(acc[r]);
        }
    }
}

// ---------------- kernel 2: encoder + 64 leapfrog steps (R9 structure) ----------------
__global__ __launch_bounds__(TMAIN) void k_main(
    const float* __restrict__ z, const float* __restrict__ W1,
    const float* __restrict__ b1, const float* __restrict__ W2,
    const float* __restrict__ b2, const float* __restrict__ w3,
    const float* __restrict__ qW, const float* __restrict__ qb,
    const float* __restrict__ pW, const float* __restrict__ pb,
    const int* __restrict__ nsp, const char* __restrict__ ws,
    float* __restrict__ out)
{
    __shared__ __align__(16) char sQb_[ROWS*128], sPb_[ROWS*128];
    __shared__ __align__(16) char sA1_[ROWS*256], sG2_[ROWS*256], sG1_[ROWS*256];
    __shared__ __align__(16) char sD1_[ROWS*512];

    const int tid = threadIdx.x;
    const int w = tid >> 6, lane = tid & 63;
    const int l15 = lane & 15, l4 = lane >> 4;
    const int sw = (l15 & 7) << 4;
    const int m0 = w * 16;
    const int wq = w & 3;
    const int mq = wq * 16;
    const bool isQ = (w >= 4);
    const int NS = *nsp;
    const float dtv = 1.0f / (float)NS;   // T_SPAN = (0,1)
    const int TS = (NS + 1) * 128;
    const int b0 = blockIdx.x * ROWS;

    const unsigned short* wsW1MT = (const unsigned short*)(ws + WS_W1MT);
    const unsigned short* wsW1T  = (const unsigned short*)(ws + WS_W1T);
    const unsigned short* wsW2T  = (const unsigned short*)(ws + WS_W2T);
    const unsigned short* wsMhi  = (const unsigned short*)(ws + WS_MHI);
    const unsigned short* wsMlo  = (const unsigned short*)(ws + WS_MLO);

    s16x8 fW1[2], fW2[4], fW2T[4], fP4[4];
    #pragma unroll
    for (int kt = 0; kt < 2; ++kt)
        fW1[kt] = ldfrag_f32(W1 + (size_t)(m0+l15)*DIM + kt*32 + 8*l4);
    #pragma unroll
    for (int kt = 0; kt < 4; ++kt){
        fW2[kt]  = ldfrag_f32(W2 + (size_t)(m0+l15)*HID + kt*32 + 8*l4);
        fW2T[kt] = *(const s16x8*)&wsW2T[(m0+l15)*HID + kt*32 + 8*l4];
    }
    {
        const unsigned short* wp4 = isQ ? wsW1MT : wsW1T;
        #pragma unroll
        for (int kt = 0; kt < 4; ++kt)
            fP4[kt] = *(const s16x8*)&wp4[(mq+l15)*HID + kt*32 + 8*l4];
    }

    const f32x4 bb1 = *(const f32x4*)&b1[m0 + 4*l4];
    const f32x4 bb2 = *(const f32x4*)&b2[m0 + 4*l4];
    const f32x4 bw3 = *(const f32x4*)&w3[m0 + 4*l4];

    // strength-reduced traj pointers (advance by 128 per step; addresses identical)
    float* ptr_q = out + (size_t)(b0+l15)*TS + mq + 4*l4;        // q slot, step 0
    float* ptr_p = out + (size_t)(b0+l15)*TS + 64 + mq + 4*l4;   // p slot, step 0

    // ---- encoder: waves4-7 -> q0, waves0-3 -> p0 (masters in registers) ----
    f32x4 master;
    {
        const float* zr = z + (size_t)(b0 + l15) * DIM;
        s16x8 bz0 = ldfrag_f32(zr + 8*l4);
        s16x8 bz1 = ldfrag_f32(zr + 32 + 8*l4);
        const float* eW = isQ ? qW : pW;
        const float* eb = isQ ? qb : pb;
        const float* wr = eW + (size_t)(mq + l15) * DIM;
        s16x8 fE0 = ldfrag_f32(wr + 8*l4);
        s16x8 fE1 = ldfrag_f32(wr + 32 + 8*l4);
        f32x4 acc = {0.f,0.f,0.f,0.f};
        acc = mfma16(fE0, bz0, acc);
        acc = mfma16(fE1, bz1, acc);
        f32x4 be = *(const f32x4*)&eb[mq + 4*l4];
        master = acc + be;
        if (isQ){
            u32x2 pr; pr[0] = pk2(master[0],master[1]); pr[1] = pk2(master[2],master[3]);
            *(u32x2*)(sQb_ + l15*128 + ((32*wq + 8*l4) ^ sw)) = pr;
        }
        *(f32x4*)(isQ ? ptr_q : ptr_p) = master;
    }
    barrier_lds();

    f32x4 vm = {0.f,0.f,0.f,0.f};
    f32x4 pend = {0.f,0.f,0.f,0.f};

    for (int t = 0; t <= NS; ++t){
        // ---- P1: deferred traj stores, then h1 = q@W1^T + b1 ----
        {
            if (t >= 1){
                if (isQ){
                    ptr_q += 128;
                    *(f32x4*)ptr_q = pend;
                } else if (t >= 2){
                    ptr_p += 128;
                    *(f32x4*)ptr_p = pend;
                }
            }
            s16x8 bq0 = *(const s16x8*)(sQb_ + l15*128 + ((16*l4) ^ sw));
            s16x8 bq1 = *(const s16x8*)(sQb_ + l15*128 + ((64 + 16*l4) ^ sw));
            f32x4 a0 = {0.f,0.f,0.f,0.f}, a1v = {0.f,0.f,0.f,0.f};
            a0 = mfma16(fW1[0], bq0, a0);
            a1v = mfma16(fW1[1], bq1, a1v);
            f32x4 si, dv;
            #pragma unroll
            for (int r = 0; r < 4; ++r){
                float h = a0[r] + a1v[r] + bb1[r];
                float sg = 1.0f / (1.0f + __expf(-h));
                float s = h * sg;
                si[r] = s;
                dv[r] = sg + s * (1.0f - sg);
            }
            u32x2 pr; pr[0] = pk2(si[0],si[1]); pr[1] = pk2(si[2],si[3]);
            *(u32x2*)(sA1_ + l15*256 + ((2*m0 + 8*l4) ^ sw)) = pr;
            *(f32x4*)(sD1_ + l15*512 + ((4*m0 + 16*l4) ^ sw)) = dv;
        }
        barrier_lds();
        // ---- P2: h2 = a1@W2^T + b2 ; g2 = w3 * silu'(h2) ----
        {
            f32x4 a0 = {0.f,0.f,0.f,0.f}, a1v = {0.f,0.f,0.f,0.f};
            #pragma unroll
            for (int kt = 0; kt < 2; ++kt){
                s16x8 ba0 = *(const s16x8*)(sA1_ + l15*256 + ((64*(2*kt) + 16*l4) ^ sw));
                s16x8 ba1 = *(const s16x8*)(sA1_ + l15*256 + ((64*(2*kt+1) + 16*l4) ^ sw));
                a0 = mfma16(fW2[2*kt], ba0, a0);
                a1v = mfma16(fW2[2*kt+1], ba1, a1v);
            }
            f32x4 g2;
            #pragma unroll
            for (int r = 0; r < 4; ++r){
                float h = a0[r] + a1v[r] + bb2[r];
                float sg = 1.0f / (1.0f + __expf(-h));
                g2[r] = bw3[r] * (sg * (1.0f + h * (1.0f - sg)));
            }
            u32x2 pr; pr[0] = pk2(g2[0],g2[1]); pr[1] = pk2(g2[2],g2[3]);
            *(u32x2*)(sG2_ + l15*256 + ((2*m0 + 8*l4) ^ sw)) = pr;
        }
        barrier_lds();
        // ---- P3: g1 = (g2 @ W2) * d1 ----
        {
            f32x4 a0 = {0.f,0.f,0.f,0.f}, a1v = {0.f,0.f,0.f,0.f};
            #pragma unroll
            for (int kt = 0; kt < 2; ++kt){
                s16x8 bg0 = *(const s16x8*)(sG2_ + l15*256 + ((64*(2*kt) + 16*l4) ^ sw));
                s16x8 bg1 = *(const s16x8*)(sG2_ + l15*256 + ((64*(2*kt+1) + 16*l4) ^ sw));
                a0 = mfma16(fW2T[2*kt], bg0, a0);
                a1v = mfma16(fW2T[2*kt+1], bg1, a1v);
            }
            f32x4 dv = *(const f32x4*)(sD1_ + l15*512 + ((4*m0 + 16*l4) ^ sw));
            f32x4 g1;
            #pragma unroll
            for (int r = 0; r < 4; ++r) g1[r] = (a0[r] + a1v[r]) * dv[r];
            u32x2 pr; pr[0] = pk2(g1[0],g1[1]); pr[1] = pk2(g1[2],g1[3]);
            *(u32x2*)(sG1_ + l15*256 + ((2*m0 + 8*l4) ^ sw)) = pr;
        }
        barrier_lds();
        // ---- P4: w<4: grad=g1@W1T -> p; w>=4: wv=g1@W1MT -> v,q ----
        if (!isQ){
            f32x4 a0 = {0.f,0.f,0.f,0.f}, a1v = {0.f,0.f,0.f,0.f};
            #pragma unroll
            for (int kt = 0; kt < 2; ++kt){
                s16x8 bg0 = *(const s16x8*)(sG1_ + l15*256 + ((64*(2*kt) + 16*l4) ^ sw));
                s16x8 bg1 = *(const s16x8*)(sG1_ + l15*256 + ((64*(2*kt+1) + 16*l4) ^ sw));
                a0 = mfma16(fP4[2*kt], bg0, a0);
                a1v = mfma16(fP4[2*kt+1], bg1, a1v);
            }
            if (t == 0){
                #pragma unroll
                for (int r = 0; r < 4; ++r) master[r] -= 0.5f * dtv * (a0[r] + a1v[r]);
                u32x2 pr; pr[0] = pk2(master[0],master[1]); pr[1] = pk2(master[2],master[3]);
                *(u32x2*)(sPb_ + l15*128 + ((32*wq + 8*l4) ^ sw)) = pr;
            } else {
                #pragma unroll
                for (int r = 0; r < 4; ++r){
                    float g = a0[r] + a1v[r];
                    pend[r] = master[r] - 0.5f * dtv * g;   // p(t)
                    master[r] -= dtv * g;                    // p_half(t+1/2)
                }
            }
        } else if (t >= 1){
            f32x4 a0 = {0.f,0.f,0.f,0.f}, a1v = {0.f,0.f,0.f,0.f};
            #pragma unroll
            for (int kt = 0; kt < 2; ++kt){
                s16x8 bg0 = *(const s16x8*)(sG1_ + l15*256 + ((64*(2*kt) + 16*l4) ^ sw));
                s16x8 bg1 = *(const s16x8*)(sG1_ + l15*256 + ((64*(2*kt+1) + 16*l4) ^ sw));
                a0 = mfma16(fP4[2*kt], bg0, a0);
                a1v = mfma16(fP4[2*kt+1], bg1, a1v);
            }
            #pragma unroll
            for (int r = 0; r < 4; ++r){
                vm[r] -= dtv * (a0[r] + a1v[r]);   // v(t+1/2)
                master[r] += dtv * vm[r];          // q(t+1)
            }
            u32x2 pr; pr[0] = pk2(master[0],master[1]); pr[1] = pk2(master[2],master[3]);
            *(u32x2*)(sQb_ + l15*128 + ((32*wq + 8*l4) ^ sw)) = pr;
            pend = master;
        }
        barrier_lds();
        // ---- one-time v init after the first half-kick ----
        if (t == 0){
            if (isQ){
                s16x8 fMhi[2], fMlo[2];
                #pragma unroll
                for (int kt = 0; kt < 2; ++kt){
                    fMhi[kt] = *(const s16x8*)&wsMhi[(mq+l15)*DIM + kt*32 + 8*l4];
                    fMlo[kt] = *(const s16x8*)&wsMlo[(mq+l15)*DIM + kt*32 + 8*l4];
                }
                s16x8 bp0 = *(const s16x8*)(sPb_ + l15*128 + ((16*l4) ^ sw));
                s16x8 bp1 = *(const s16x8*)(sPb_ + l15*128 + ((64 + 16*l4) ^ sw));
                f32x4 aH = {0.f,0.f,0.f,0.f}, aL = {0.f,0.f,0.f,0.f};
                aH = mfma16(fMhi[0], bp0, aH);
                aH = mfma16(fMhi[1], bp1, aH);
                aL = mfma16(fMlo[0], bp0, aL);
                aL = mfma16(fMlo[1], bp1, aL);
                #pragma unroll
                for (int r = 0; r < 4; ++r){
                    vm[r] = aH[r] + aL[r];         // v(1/2)
                    master[r] += dtv * vm[r];      // q(1)
                }
                u32x2 pr; pr[0] = pk2(master[0],master[1]); pr[1] = pk2(master[2],master[3]);
                *(u32x2*)(sQb_ + l15*128 + ((32*wq + 8*l4) ^ sw)) = pr;
                pend = master;
            }
            barrier_lds();
        }
    }
    // flush last p-traj
    if (!isQ)
        *(f32x4*)(ptr_p + 128) = pend;
}

extern "C" void kernel_launch(void* const* d_in, const int* in_sizes, int n_in,
                              void* d_out, int out_size, void* d_ws, size_t ws_size,
                              hipStream_t stream)
{
    const float* z  = (const float*)d_in[0];
    const float* L  = (const float*)d_in[1];
    const float* W1 = (const float*)d_in[2];
    const float* b1 = (const float*)d_in[3];
    const float* W2 = (const float*)d_in[4];
    const float* b2 = (const float*)d_in[5];
    const float* w3 = (const float*)d_in[6];
    // d_in[7] = Vb3: constant, vanishes in gradV
    const float* qW = (const float*)d_in[8];
    const float* qb = (const float*)d_in[9];
    const float* pW = (const float*)d_in[10];
    const float* pb = (const float*)d_in[11];
    const int* nsp  = (const int*)d_in[12];
    float* out = (float*)d_out;
    char* ws = (char*)d_ws;
    const int B = in_sizes[0] / DIM;

    k_prep<<<2, 512, 0, stream>>>(L, W1, W2, ws);
    k_main<<<B/ROWS, TMAIN, 0, stream>>>(z, W1, b1, W2, b2, w3, qW, qb, pW, pb, nsp, ws, out);
}